// Round 1
// 387.911 us; speedup vs baseline: 1.0194x; 1.0194x over previous
//
#include <hip/hip_runtime.h>
#include <hip/hip_bf16.h>
#include <math.h>

// ---------------------------------------------------------------------------
// GCN 3-layer forward. R9: CSR rows padded to multiples of 8 edges with a
// dummy zero row (index n, zeroed by GEMM epilogue). Gathers read cs as one
// aligned uint4 per 8 edges (wave-uniform -> s_load path), no tail masks,
// software-prefetched. k_dis folded into scan_final; deg-zero + cs-prefill
// merged. Norm folded into features (GEMM epilogue stores hs = dis*h, bf16).
// ---------------------------------------------------------------------------

using short8  = __attribute__((ext_vector_type(8))) short;
using floatx4 = __attribute__((ext_vector_type(4))) float;

__device__ inline float bf2f(unsigned int u16) {
    union { unsigned int i; float f; } x; x.i = u16 << 16; return x.f;
}
__device__ inline unsigned short f2bf(float f) {
    union { float f; unsigned int i; } x; x.f = f;
    unsigned int lsb = (x.i >> 16) & 1u;
    return (unsigned short)((x.i + 0x7fffu + lsb) >> 16);
}

// ---------------- init: zero deg + prefill cs with dummy node id -----------
__global__ void k_init(int* deg, unsigned int* csw, int n, int words, unsigned int val) {
    int i = blockIdx.x * 256 + threadIdx.x;
    if (i < n) deg[i] = 0;
    if (i < words) csw[i] = val;
}

__global__ void k_deg_count(const int* __restrict__ dst, int* deg, int e) {
    int i = blockIdx.x * 256 + threadIdx.x;
    if (i < e) atomicAdd(&deg[dst[i]], 1);
}

// scan over PADDED degrees: pdeg = ceil8(deg)
__global__ void k_scan_block(const int* __restrict__ deg, int* incl, int* bsum, int n) {
    __shared__ int s[256];
    int tid = threadIdx.x;
    int i = blockIdx.x * 256 + tid;
    int v = (i < n) ? ((deg[i] + 7) & ~7) : 0;
    s[tid] = v;
    __syncthreads();
    for (int off = 1; off < 256; off <<= 1) {
        int t = (tid >= off) ? s[tid - off] : 0;
        __syncthreads();
        s[tid] += t;
        __syncthreads();
    }
    if (i < n) incl[i] = s[tid];
    if (tid == 255) bsum[blockIdx.x] = s[255];
}

__global__ void k_scan_bsum(int* bsum, int nb) {   // single block, nb <= 256
    __shared__ int s[256];
    int tid = threadIdx.x;
    s[tid] = (tid < nb) ? bsum[tid] : 0;
    __syncthreads();
    for (int off = 1; off < 256; off <<= 1) {
        int t = (tid >= off) ? s[tid - off] : 0;
        __syncthreads();
        s[tid] += t;
        __syncthreads();
    }
    if (tid < nb) bsum[tid] = s[tid];
}

// final: row_start/cursor from padded scan, plus dis = rsqrt(deg+1)
__global__ void k_scan_final(const int* __restrict__ deg, const int* __restrict__ incl,
                             const int* __restrict__ bsum, int* row_start, int* cursor,
                             float* dis, int n) {
    int i = blockIdx.x * 256 + threadIdx.x;
    if (i >= n) return;
    int base = (blockIdx.x > 0) ? bsum[blockIdx.x - 1] : 0;
    int d = deg[i];
    int pd = (d + 7) & ~7;
    int excl = base + incl[i] - pd;
    row_start[i] = excl;
    cursor[i] = excl;
    dis[i] = rsqrtf((float)(d + 1));   // +1 self loop
    if (i == n - 1) row_start[n] = excl + pd;
}

// 2 B payload per edge: cs[pos] = src node id (uint16, n < 65536).
// Padding slots keep the prefill value n (dummy zero row).
__global__ void k_csr_fill16(const int* __restrict__ src, const int* __restrict__ dst,
                             int* cursor, unsigned short* __restrict__ cs, int e) {
    int i = blockIdx.x * 256 + threadIdx.x;
    if (i >= e) return;
    int s = src[i], d = dst[i];
    int pos = atomicAdd(&cursor[d], 1);
    cs[pos] = (unsigned short)s;
}

// ---------------- all W transposes + bf16 cast in one dispatch -------------
__global__ void k_wt_all(const float* __restrict__ W1, const float* __restrict__ W2,
                         const float* __restrict__ W3,
                         unsigned short* __restrict__ Wt1, unsigned short* __restrict__ Wt2,
                         unsigned short* __restrict__ Wt3) {
    int i = blockIdx.x * 256 + threadIdx.x;
    if (i < 512 * 128) {
        int k = i / 128, f = i % 128;
        Wt1[(size_t)f * 512 + k] = f2bf(W1[i]);
    } else if (i < 512 * 128 + 128 * 128) {
        int j = i - 512 * 128;
        int k = j / 128, f = j % 128;
        Wt2[(size_t)f * 128 + k] = f2bf(W2[j]);
    } else if (i < 512 * 128 + 128 * 128 + 128 * 64) {
        int j = i - (512 * 128 + 128 * 128);
        int k = j / 64, f = j % 64;
        Wt3[(size_t)f * 128 + k] = f2bf(W3[j]);
    }
}

// ---------------- GEMM: whole-B-in-LDS, epilogue scales by dis[row] --------
// C[(n+1) x BN](bf16) = dis[row] * (A[n x K] @ Wt^T); row n written as zeros.
template <int K, int BN, bool A_BF16>
__global__ __launch_bounds__(256) void k_gemm_bl(const void* __restrict__ Av,
                                                 const unsigned short* __restrict__ Wt,
                                                 const float* __restrict__ dis,
                                                 unsigned short* __restrict__ C, int n) {
    constexpr int KC = 128;                   // K-chunk staged per barrier
    constexpr int NCH = K / KC;
    constexpr int NT = BN / 16;
    constexpr int LDB = KC + 8;               // padded (272 B stride)
    __shared__ unsigned short Bs[BN][LDB];

    const int tid = threadIdx.x;
    const int wv = tid >> 6;
    const int lane = tid & 63;
    const int m = lane & 15;
    const int quad = lane >> 4;
    const int rowb = blockIdx.x * 64 + wv * 16;
    const int r0 = min(rowb + m, n - 1);      // clamped loads; stores guarded

    floatx4 acc[NT] = {};

    for (int ch = 0; ch < NCH; ++ch) {
        const int kc = ch * KC;
        if (ch > 0) __syncthreads();
#pragma unroll
        for (int l = 0; l < (BN * KC) / (256 * 8); ++l) {
            int id = tid + l * 256;
            int row = id / (KC / 8);
            int p = id % (KC / 8);
            *(uint4*)&Bs[row][p * 8] = *(const uint4*)&Wt[(size_t)row * K + kc + p * 8];
        }
        __syncthreads();

#pragma unroll
        for (int ki = 0; ki < KC / 32; ++ki) {
            const int k = kc + ki * 32;
            short8 a;
            if constexpr (A_BF16) {
                const unsigned short* A = (const unsigned short*)Av;
                a = *(const short8*)&A[(size_t)r0 * K + k + quad * 8];
            } else {
                const float* A = (const float*)Av;
                float4 f0 = *(const float4*)&A[(size_t)r0 * K + k + quad * 8];
                float4 f1 = *(const float4*)&A[(size_t)r0 * K + k + quad * 8 + 4];
                a[0] = (short)f2bf(f0.x); a[1] = (short)f2bf(f0.y);
                a[2] = (short)f2bf(f0.z); a[3] = (short)f2bf(f0.w);
                a[4] = (short)f2bf(f1.x); a[5] = (short)f2bf(f1.y);
                a[6] = (short)f2bf(f1.z); a[7] = (short)f2bf(f1.w);
            }
#pragma unroll
            for (int t = 0; t < NT; ++t) {
                short8 b = *(const short8*)&Bs[t * 16 + m][ki * 32 + quad * 8];
                acc[t] = __builtin_amdgcn_mfma_f32_16x16x32_bf16(a, b, acc[t], 0, 0, 0);
            }
        }
    }

    // C/D layout: col = lane&15, row = quad*4 + reg; scale by dis[row]
#pragma unroll
    for (int r = 0; r < 4; ++r) {
        int ga = rowb + quad * 4 + r;
        if (ga < n) {
            float dr = dis[ga];
#pragma unroll
            for (int t = 0; t < NT; ++t)
                C[(size_t)ga * BN + t * 16 + m] = f2bf(acc[t][r] * dr);
        } else if (ga == n) {                 // dummy zero row for padded edges
#pragma unroll
            for (int t = 0; t < NT; ++t)
                C[(size_t)n * BN + t * 16 + m] = 0;
        }
    }
}

// ---------------- Gather F=128: out = ep(dis[d]*(hs[d]+sum hs[s]) + b) -----
// Rows padded to x8 edges; cs read as one aligned uint4 per 8 edges
// (wave-uniform address -> scalar path), prefetched one iteration ahead.
template <bool RELU>
__global__ __launch_bounds__(256) void k_gather128(
        const int* __restrict__ rs, const unsigned short* __restrict__ cs,
        const float* __restrict__ dis,
        const unsigned short* __restrict__ h, const float* __restrict__ bias,
        unsigned short* __restrict__ out, int n) {
    int wid = (blockIdx.x * 256 + threadIdx.x) >> 6;
    int node = __builtin_amdgcn_readfirstlane(wid);
    int lane = threadIdx.x & 63;
    if (node >= n) return;
    int c = lane * 2;
    unsigned int hv = *(const unsigned int*)&h[(size_t)node * 128 + c];
    float ax0 = bf2f(hv & 0xffffu);
    float ay0 = bf2f(hv >> 16);
    float ax1 = 0.f, ay1 = 0.f, ax2 = 0.f, ay2 = 0.f, ax3 = 0.f, ay3 = 0.f;
    int beg = rs[node], end = rs[node + 1];
    if (beg < end) {
        uint4 q = *(const uint4*)&cs[beg];
        for (int j = beg; j < end; j += 8) {
            uint4 qn = *(const uint4*)&cs[min(j + 8, end - 8)];   // prefetch
            int s0 = q.x & 0xffff, s1 = q.x >> 16;
            int s2 = q.y & 0xffff, s3 = q.y >> 16;
            int s4 = q.z & 0xffff, s5 = q.z >> 16;
            int s6 = q.w & 0xffff, s7 = q.w >> 16;
            unsigned int v0 = *(const unsigned int*)&h[(size_t)s0 * 128 + c];
            unsigned int v1 = *(const unsigned int*)&h[(size_t)s1 * 128 + c];
            unsigned int v2 = *(const unsigned int*)&h[(size_t)s2 * 128 + c];
            unsigned int v3 = *(const unsigned int*)&h[(size_t)s3 * 128 + c];
            unsigned int v4 = *(const unsigned int*)&h[(size_t)s4 * 128 + c];
            unsigned int v5 = *(const unsigned int*)&h[(size_t)s5 * 128 + c];
            unsigned int v6 = *(const unsigned int*)&h[(size_t)s6 * 128 + c];
            unsigned int v7 = *(const unsigned int*)&h[(size_t)s7 * 128 + c];
            ax0 += bf2f(v0 & 0xffffu) + bf2f(v1 & 0xffffu);
            ay0 += bf2f(v0 >> 16)     + bf2f(v1 >> 16);
            ax1 += bf2f(v2 & 0xffffu) + bf2f(v3 & 0xffffu);
            ay1 += bf2f(v2 >> 16)     + bf2f(v3 >> 16);
            ax2 += bf2f(v4 & 0xffffu) + bf2f(v5 & 0xffffu);
            ay2 += bf2f(v4 >> 16)     + bf2f(v5 >> 16);
            ax3 += bf2f(v6 & 0xffffu) + bf2f(v7 & 0xffffu);
            ay3 += bf2f(v6 >> 16)     + bf2f(v7 >> 16);
            q = qn;
        }
    }
    float di = dis[node];
    float2 bb = *(const float2*)&bias[c];
    float ax = ((ax0 + ax1) + (ax2 + ax3)) * di + bb.x;
    float ay = ((ay0 + ay1) + (ay2 + ay3)) * di + bb.y;
    if (RELU) { ax = fmaxf(ax, 0.f); ay = fmaxf(ay, 0.f); }
    unsigned int o = (unsigned int)f2bf(ax) | ((unsigned int)f2bf(ay) << 16);
    *(unsigned int*)&out[(size_t)node * 128 + c] = o;
}

// ---------------- Gather F=64 + bias + log_softmax (fp32 out) --------------
__global__ __launch_bounds__(256) void k_gather64_lsm(
        const int* __restrict__ rs, const unsigned short* __restrict__ cs,
        const float* __restrict__ dis,
        const unsigned short* __restrict__ h, const float* __restrict__ bias,
        float* __restrict__ out, int n) {
    int wid = (blockIdx.x * 256 + threadIdx.x) >> 6;
    int node = __builtin_amdgcn_readfirstlane(wid);
    int lane = threadIdx.x & 63;
    if (node >= n) return;
    float a0 = bf2f(h[(size_t)node * 64 + lane]);
    float a1 = 0.f, a2 = 0.f, a3 = 0.f;
    int beg = rs[node], end = rs[node + 1];
    if (beg < end) {
        uint4 q = *(const uint4*)&cs[beg];
        for (int j = beg; j < end; j += 8) {
            uint4 qn = *(const uint4*)&cs[min(j + 8, end - 8)];   // prefetch
            int s0 = q.x & 0xffff, s1 = q.x >> 16;
            int s2 = q.y & 0xffff, s3 = q.y >> 16;
            int s4 = q.z & 0xffff, s5 = q.z >> 16;
            int s6 = q.w & 0xffff, s7 = q.w >> 16;
            float h0 = bf2f(h[(size_t)s0 * 64 + lane]);
            float h1 = bf2f(h[(size_t)s1 * 64 + lane]);
            float h2 = bf2f(h[(size_t)s2 * 64 + lane]);
            float h3 = bf2f(h[(size_t)s3 * 64 + lane]);
            float h4 = bf2f(h[(size_t)s4 * 64 + lane]);
            float h5 = bf2f(h[(size_t)s5 * 64 + lane]);
            float h6 = bf2f(h[(size_t)s6 * 64 + lane]);
            float h7 = bf2f(h[(size_t)s7 * 64 + lane]);
            a0 += h0 + h1;
            a1 += h2 + h3;
            a2 += h4 + h5;
            a3 += h6 + h7;
            q = qn;
        }
    }
    float v = ((a0 + a1) + (a2 + a3)) * dis[node] + bias[lane];
    float mm = v;
#pragma unroll
    for (int s = 32; s; s >>= 1) mm = fmaxf(mm, __shfl_xor(mm, s));
    float e = expf(v - mm);
    float sum = e;
#pragma unroll
    for (int s = 32; s; s >>= 1) sum += __shfl_xor(sum, s);
    out[(size_t)node * 64 + lane] = (v - mm) - logf(sum);
}

extern "C" void kernel_launch(void* const* d_in, const int* in_sizes, int n_in,
                              void* d_out, int out_size, void* d_ws, size_t ws_size,
                              hipStream_t stream) {
    constexpr int IN = 512, HID = 128, OUT = 64;
    const float* feats = (const float*)d_in[0];
    const int*   adj   = (const int*)d_in[1];
    const float* W1 = (const float*)d_in[2];
    const float* b1 = (const float*)d_in[3];
    const float* W2 = (const float*)d_in[4];
    const float* b2 = (const float*)d_in[5];
    const float* W3 = (const float*)d_in[6];
    const float* b3 = (const float*)d_in[7];
    float* out = (float*)d_out;

    const int n = in_sizes[0] / IN;      // 50000
    const int e = in_sizes[1] / 2;       // 800000
    const int* srcp = adj;
    const int* dstp = adj + e;

    const int e_pad_max = e + 7 * n + 16;            // padded edge capacity
    const int csw_words = (e + 7 * n) / 2 + 8;       // uint words to prefill

    // workspace layout (16B-aligned chunks)
    char* ws = (char*)d_ws;
    auto align16 = [](char* p) { return (char*)(((uintptr_t)p + 15) & ~(uintptr_t)15); };
    int*   deg  = (int*)ws;                    ws += (size_t)n * 4;
    float* dis  = (float*)ws;                  ws += (size_t)n * 4;
    int*   incl = (int*)ws;                    ws += (size_t)n * 4;
    int*   bsum = (int*)ws;                    ws += 256 * 4;
    int*   rs   = (int*)ws;                    ws += (size_t)(n + 1) * 4;
    int*   curs = (int*)ws;                    ws += (size_t)n * 4;
    ws = align16(ws);
    unsigned short* cs  = (unsigned short*)ws; ws += (size_t)e_pad_max * 2;
    ws = align16(ws);
    unsigned short* Wt1 = (unsigned short*)ws; ws += (size_t)IN * HID * 2;
    unsigned short* Wt2 = (unsigned short*)ws; ws += (size_t)HID * HID * 2;
    unsigned short* Wt3 = (unsigned short*)ws; ws += (size_t)HID * OUT * 2;
    ws = align16(ws);
    unsigned short* hb  = (unsigned short*)ws; ws += (size_t)(n + 1) * HID * 2;  // +dummy row n
    ws = align16(ws);
    unsigned short* xb  = (unsigned short*)ws; ws += (size_t)(n + 1) * HID * 2;

    const int nb_n = (n + 255) / 256;
    const int nb_e = (e + 255) / 256;
    const int nb_g = n / 64 + 1;             // GEMM blocks — always covers row n
    const int nb_w = (n * 64 + 255) / 256;   // 1 wave/node kernels
    const int nb_wt = (IN * HID + HID * HID + HID * OUT + 255) / 256;
    const int nb_init = (max(n, csw_words) + 255) / 256;
    const unsigned int fillv = ((unsigned int)n << 16) | (unsigned int)n;

    // ---- build padded CSR (by dst) + symmetric norm
    k_init<<<nb_init, 256, 0, stream>>>(deg, (unsigned int*)cs, n, csw_words, fillv);
    k_deg_count<<<nb_e, 256, 0, stream>>>(dstp, deg, e);
    k_scan_block<<<nb_n, 256, 0, stream>>>(deg, incl, bsum, n);
    k_scan_bsum<<<1, 256, 0, stream>>>(bsum, nb_n);
    k_scan_final<<<nb_n, 256, 0, stream>>>(deg, incl, bsum, rs, curs, dis, n);
    k_csr_fill16<<<nb_e, 256, 0, stream>>>(srcp, dstp, curs, cs, e);

    // ---- weight transposes (fp32 -> bf16, [K][F] -> [F][K]), one dispatch
    k_wt_all<<<nb_wt, 256, 0, stream>>>(W1, W2, W3, Wt1, Wt2, Wt3);

    // ---- layer 1: 512 -> 128
    k_gemm_bl<IN, HID, false><<<nb_g, 256, 0, stream>>>(feats, Wt1, dis, hb, n);
    k_gather128<true><<<nb_w, 256, 0, stream>>>(rs, cs, dis, hb, b1, xb, n);

    // ---- layer 2: 128 -> 128
    k_gemm_bl<HID, HID, true><<<nb_g, 256, 0, stream>>>(xb, Wt2, dis, hb, n);
    k_gather128<true><<<nb_w, 256, 0, stream>>>(rs, cs, dis, hb, b2, xb, n);

    // ---- layer 3: 128 -> 64
    k_gemm_bl<HID, OUT, true><<<nb_g, 256, 0, stream>>>(xb, Wt3, dis, hb, n);
    k_gather64_lsm<<<nb_w, 256, 0, stream>>>(rs, cs, dis, hb, b3, out, n);
}